// Round 4
// baseline (893.518 us; speedup 1.0000x reference)
//
#include <hip/hip_runtime.h>
#include <math.h>

#define T_TOK 2048
#define HD    2048
#define NEXP  64
#define KTOP  8
#define FD    768
#define CAPE  512

typedef float  f32x4 __attribute__((ext_vector_type(4)));
typedef __bf16 bf16x8 __attribute__((ext_vector_type(8)));
typedef __bf16 bf16x4 __attribute__((ext_vector_type(4)));

__device__ __forceinline__ void load_lds16(const void* g, void* l) {
  __builtin_amdgcn_global_load_lds(
      (const __attribute__((address_space(1))) unsigned int*)g,
      (__attribute__((address_space(3))) unsigned int*)l, 16, 0, 0);
}

#define WAITCNT(S) asm volatile(S ::: "memory")
#define BARRIER()  __builtin_amdgcn_s_barrier()

// ---------------- Kernel 1: router (4 tokens per block) + fused f32->bf16 ----------------
__global__ __launch_bounds__(256) void router_kernel(
    const float* __restrict__ x, const float* __restrict__ rw,
    int* __restrict__ cnt, int* __restrict__ tok_list, float* __restrict__ w_list,
    unsigned short* __restrict__ xb)
{
  const int t = threadIdx.x;
  const int tb = blockIdx.x * 4;
  __shared__ float xs[4][HD];
  __shared__ float lg[4][NEXP];

  const float4* xsrc = (const float4*)(x + (size_t)tb * HD);
  float4* xdst = (float4*)&xs[0][0];
  for (int i = t; i < 4 * HD / 4; i += 256) xdst[i] = xsrc[i];
  __syncthreads();

  {
    const int e = t >> 2, q = t & 3;
    const float* wrow = rw + (size_t)e * HD;
    float a0 = 0.f, a1 = 0.f, a2 = 0.f, a3 = 0.f;
    for (int i = 0; i < HD / 16; ++i) {
      int h = (i * 4 + q) * 4;
      float4 wv = *(const float4*)(wrow + h);
      float4 x0 = *(const float4*)&xs[0][h];
      float4 x1 = *(const float4*)&xs[1][h];
      float4 x2 = *(const float4*)&xs[2][h];
      float4 x3 = *(const float4*)&xs[3][h];
      a0 += wv.x*x0.x + wv.y*x0.y + wv.z*x0.z + wv.w*x0.w;
      a1 += wv.x*x1.x + wv.y*x1.y + wv.z*x1.z + wv.w*x1.w;
      a2 += wv.x*x2.x + wv.y*x2.y + wv.z*x2.z + wv.w*x2.w;
      a3 += wv.x*x3.x + wv.y*x3.y + wv.z*x3.z + wv.w*x3.w;
    }
    a0 += __shfl_xor(a0, 1); a0 += __shfl_xor(a0, 2);
    a1 += __shfl_xor(a1, 1); a1 += __shfl_xor(a1, 2);
    a2 += __shfl_xor(a2, 1); a2 += __shfl_xor(a2, 2);
    a3 += __shfl_xor(a3, 1); a3 += __shfl_xor(a3, 2);
    if (q == 0) { lg[0][e] = a0; lg[1][e] = a1; lg[2][e] = a2; lg[3][e] = a3; }
  }

  // fused convert of this block's 4 tokens (x rows are L1/L2-hot)
  {
    const f32x4* xs4 = (const f32x4*)(x + (size_t)tb * HD);
    bf16x4* xbd = (bf16x4*)(xb + (size_t)tb * HD);
    #pragma unroll
    for (int j = 0; j < 8; ++j) {
      f32x4 v = xs4[j * 256 + t];
      xbd[j * 256 + t] = (bf16x4){(__bf16)v[0], (__bf16)v[1], (__bf16)v[2], (__bf16)v[3]};
    }
  }
  __syncthreads();

  const int wid = t >> 6, lane = t & 63;
  float v = lg[wid][lane];
  float mx = v;
  for (int o = 32; o; o >>= 1) mx = fmaxf(mx, __shfl_xor(mx, o));
  float p = expf(v - mx);
  float s = p;
  for (int o = 32; o; o >>= 1) s += __shfl_xor(s, o);
  float prob = p / s;

  float r = prob;
  float wk[KTOP]; int ik[KTOP]; float wsum = 0.f;
  #pragma unroll
  for (int k = 0; k < KTOP; ++k) {
    float bv = r; int bl = lane;
    for (int o = 32; o; o >>= 1) {
      float ov = __shfl_xor(bv, o); int ol = __shfl_xor(bl, o);
      if (ov > bv || (ov == bv && ol < bl)) { bv = ov; bl = ol; }
    }
    wk[k] = bv; ik[k] = bl; wsum += bv;
    if (lane == bl) r = -1.f;
  }
  if (lane == 0) {
    float inv = 1.f / (wsum + 1e-20f);
    int token = tb + wid;
    #pragma unroll
    for (int k = 0; k < KTOP; ++k) {
      int ex = ik[k];
      int pos = atomicAdd(&cnt[ex], 1);
      if (pos < CAPE) {
        tok_list[ex * CAPE + pos] = token;
        w_list[ex * CAPE + pos] = wk[k] * inv;
      }
    }
  }
}

// ============ GEMM building blocks ============
// B LDS: [n][k] single-buffered, stride 72 shorts (144B), XOR swizzle ((n>>2)&7)<<3.
// A LDS: [m][k] double-buffered linear granules via global_load_lds, src pre-swizzled,
//        reads XOR ((row&7)<<4) bytes. 2 barriers per K-step (m97 shape), counted vmcnt.

// ---------------- Kernel 3: gate/up GEMM + SiLU -> hmid (bf16) ----------------
__global__ __launch_bounds__(256, 3) void gateup_kernel(
    const unsigned short* __restrict__ xb,
    const float* __restrict__ wg, const float* __restrict__ wu,
    const int* __restrict__ cnt, const int* __restrict__ tok_list,
    unsigned short* __restrict__ hmid)
{
  const int nt = blockIdx.x, mt = blockIdx.y, e = blockIdx.z;
  int ne = cnt[e]; ne = ne < CAPE ? ne : CAPE;
  if (mt * 128 >= ne) return;
  const int t = threadIdx.x, lane = t & 63, wid = t >> 6;
  const int wr = wid >> 1, wc = wid & 1;

  __shared__ __align__(16) unsigned short A[2 * 128 * 64];   // 32 KB dbuf
  __shared__ __align__(16) unsigned short Bg[64 * 72];       // 9 KB single
  __shared__ __align__(16) unsigned short Bu[64 * 72];
  __shared__ int toks[128];

  if (t < 128) {
    int r = mt * 128 + t;
    toks[t] = tok_list[e * CAPE + (r < ne ? r : 0)];
  }
  __syncthreads();

  const unsigned short* asrc[4];
  #pragma unroll
  for (int i = 0; i < 4; ++i) {
    const int inst = wid * 4 + i;
    const int G = inst * 64 + lane;
    const int m = G >> 3, gg = G & 7;
    asrc[i] = xb + (size_t)toks[m] * HD + 8 * (gg ^ (m & 7));
  }

  f32x4 z4 = {0.f, 0.f, 0.f, 0.f};
  f32x4 gacc[4][2], uacc[4][2];
  #pragma unroll
  for (int i = 0; i < 4; ++i)
    #pragma unroll
    for (int j = 0; j < 2; ++j) { gacc[i][j] = z4; uacc[i][j] = z4; }

  const size_t wbase = (size_t)e * HD * FD + (size_t)nt * 64;
  const int nc = t & 15, kc = t >> 4;
  f32x4 Ra[8], Rb[8];

#define LOAD_GU(K0, R) do { \
    const float* pg_ = wg + wbase + (size_t)((K0) + kc * 4) * FD + nc * 4; \
    const float* pu_ = wu + wbase + (size_t)((K0) + kc * 4) * FD + nc * 4; \
    R[0] = *(const f32x4*)pg_;            R[1] = *(const f32x4*)(pg_ + FD); \
    R[2] = *(const f32x4*)(pg_ + 2*FD);   R[3] = *(const f32x4*)(pg_ + 3*FD); \
    R[4] = *(const f32x4*)pu_;            R[5] = *(const f32x4*)(pu_ + FD); \
    R[6] = *(const f32x4*)(pu_ + 2*FD);   R[7] = *(const f32x4*)(pu_ + 3*FD); \
  } while (0)

#define STAGE_A4(KT, BUF) do { \
    const int k0s_ = (KT) * 64; \
    _Pragma("unroll") \
    for (int i_ = 0; i_ < 4; ++i_) \
      load_lds16(asrc[i_] + k0s_, &A[(BUF) * 8192 + (wid * 4 + i_) * 512]); \
  } while (0)

#define CVT_GU(R) do { \
    __bf16* bg_ = (__bf16*)Bg; \
    __bf16* bu_ = (__bf16*)Bu; \
    const int xm_ = (nc & 7) << 3; \
    _Pragma("unroll") \
    for (int j_ = 0; j_ < 4; ++j_) { \
      int so_ = (nc * 4 + j_) * 72 + ((kc * 4) ^ xm_); \
      *(bf16x4*)&bg_[so_] = (bf16x4){(__bf16)R[0][j_], (__bf16)R[1][j_], (__bf16)R[2][j_], (__bf16)R[3][j_]}; \
      *(bf16x4*)&bu_[so_] = (bf16x4){(__bf16)R[4][j_], (__bf16)R[5][j_], (__bf16)R[6][j_], (__bf16)R[7][j_]}; \
    } \
  } while (0)

#define COMPUTE_GU(CUR) do { \
    const char* Ab_ = (const char*)&A[(CUR) * 8192]; \
    const __bf16* Bg_ = (const __bf16*)Bg; \
    const __bf16* Bu_ = (const __bf16*)Bu; \
    _Pragma("unroll") \
    for (int ks = 0; ks < 2; ++ks) { \
      bf16x8 af[4]; \
      _Pragma("unroll") \
      for (int mf = 0; mf < 4; ++mf) { \
        int row = wr * 64 + mf * 16 + (lane & 15); \
        int byte = row * 128 + (lane >> 4) * 16 + ks * 64; \
        byte ^= (row & 7) << 4; \
        af[mf] = *(const bf16x8*)(Ab_ + byte); \
      } \
      _Pragma("unroll") \
      for (int nf = 0; nf < 2; ++nf) { \
        int n = wc * 32 + nf * 16 + (lane & 15); \
        int so = n * 72 + ((((lane >> 4) * 8) + ks * 32) ^ (((n >> 2) & 7) << 3)); \
        bf16x8 bgf = *(const bf16x8*)&Bg_[so]; \
        bf16x8 bum = *(const bf16x8*)&Bu_[so]; \
        _Pragma("unroll") \
        for (int mf = 0; mf < 4; ++mf) { \
          gacc[mf][nf] = __builtin_amdgcn_mfma_f32_16x16x32_bf16(af[mf], bgf, gacc[mf][nf], 0, 0, 0); \
          uacc[mf][nf] = __builtin_amdgcn_mfma_f32_16x16x32_bf16(af[mf], bum, uacc[mf][nf], 0, 0, 0); \
        } \
      } \
    } \
  } while (0)

  // prologue: tile0 into A-buf0 + B; tile1 regs in flight
  LOAD_GU(0, Ra);          // 8 vm
  STAGE_A4(0, 0);          // +4
  LOAD_GU(64, Rb);         // +8 -> 20
  WAITCNT("s_waitcnt vmcnt(12)");            // Ra done
  CVT_GU(Ra);
  WAITCNT("s_waitcnt vmcnt(8) lgkmcnt(0)");  // A(0) done; Rb flies
  BARRIER();

  // main: 15 double-steps, computes tiles 0..29
  for (int i = 0; i < 15; ++i) {
    const int kt = 2 * i;
    STAGE_A4(kt + 1, 1);
    LOAD_GU((kt + 2) * 64, Ra);
    COMPUTE_GU(0);
    WAITCNT("s_waitcnt lgkmcnt(0)");
    BARRIER();                                 // all waves done reading B(kt)
    WAITCNT("s_waitcnt vmcnt(12)");            // Rb (tile kt+1) done
    CVT_GU(Rb);
    WAITCNT("s_waitcnt vmcnt(8) lgkmcnt(0)");  // A(kt+1) done; Ra flies
    BARRIER();

    STAGE_A4(kt + 2, 0);
    LOAD_GU((kt + 3) * 64, Rb);
    COMPUTE_GU(1);
    WAITCNT("s_waitcnt lgkmcnt(0)");
    BARRIER();
    WAITCNT("s_waitcnt vmcnt(12)");            // Ra (tile kt+2) done
    CVT_GU(Ra);
    WAITCNT("s_waitcnt vmcnt(8) lgkmcnt(0)");  // A(kt+2) done; Rb flies
    BARRIER();
  }
  // tail: tiles 30, 31  (Rb holds tile31; outstanding vm = 8)
  STAGE_A4(31, 1);
  COMPUTE_GU(0);
  WAITCNT("s_waitcnt lgkmcnt(0)");
  BARRIER();
  WAITCNT("s_waitcnt vmcnt(4)");               // Rb done (A(31) may fly)
  CVT_GU(Rb);
  WAITCNT("s_waitcnt vmcnt(0) lgkmcnt(0)");
  BARRIER();
  COMPUTE_GU(1);

#undef LOAD_GU
#undef STAGE_A4
#undef CVT_GU
#undef COMPUTE_GU

  // epilogue: hmid = silu(g)*u   (D layout: col=lane&15, row=4*(lane>>4)+reg)
  const size_t hbase = (size_t)e * CAPE + (size_t)mt * 128;
  __bf16* hm = (__bf16*)hmid;
  #pragma unroll
  for (int mf = 0; mf < 4; ++mf) {
    #pragma unroll
    for (int nf = 0; nf < 2; ++nf) {
      #pragma unroll
      for (int r = 0; r < 4; ++r) {
        int row = wr * 64 + mf * 16 + (lane >> 4) * 4 + r;
        int c = nt * 64 + wc * 32 + nf * 16 + (lane & 15);
        float gv = gacc[mf][nf][r], uv = uacc[mf][nf][r];
        float hv = gv / (1.f + __expf(-gv)) * uv;
        hm[(hbase + row) * FD + c] = (__bf16)hv;
      }
    }
  }
}

// ---------------- Kernel 4: down GEMM + weighted scatter-add ----------------
__global__ __launch_bounds__(256, 3) void down_kernel(
    const unsigned short* __restrict__ hmid,
    const float* __restrict__ wd,
    const int* __restrict__ cnt, const int* __restrict__ tok_list,
    const float* __restrict__ w_list, float* __restrict__ out)
{
  const int nt = blockIdx.x, mt = blockIdx.y, e = blockIdx.z;
  int ne = cnt[e]; ne = ne < CAPE ? ne : CAPE;
  if (mt * 128 >= ne) return;
  const int t = threadIdx.x, lane = t & 63, wid = t >> 6;
  const int wr = wid >> 1, wc = wid & 1;

  __shared__ __align__(16) unsigned short A[2 * 128 * 64];
  __shared__ __align__(16) unsigned short Bd[64 * 72];
  __shared__ int toks[128];
  __shared__ float wts[128];

  if (t < 128) {
    int r = mt * 128 + t;
    bool vv = r < ne;
    toks[t] = vv ? tok_list[e * CAPE + r] : 0;
    wts[t]  = vv ? w_list[e * CAPE + r] : 0.f;
  }
  __syncthreads();

  const size_t arow = (size_t)e * CAPE + (size_t)mt * 128;
  const unsigned short* asrc[4];
  #pragma unroll
  for (int i = 0; i < 4; ++i) {
    const int inst = wid * 4 + i;
    const int G = inst * 64 + lane;
    const int m = G >> 3, gg = G & 7;
    asrc[i] = hmid + (arow + m) * FD + 8 * (gg ^ (m & 7));
  }

  f32x4 z4 = {0.f, 0.f, 0.f, 0.f};
  f32x4 dacc[4][2];
  #pragma unroll
  for (int i = 0; i < 4; ++i)
    #pragma unroll
    for (int j = 0; j < 2; ++j) dacc[i][j] = z4;

  const size_t wbase = (size_t)e * FD * HD + (size_t)nt * 64;
  const int nc = t & 15, kc = t >> 4;
  f32x4 Ra[4], Rb[4];

#define LOAD_D(K0, R) do { \
    const float* pd_ = wd + wbase + (size_t)((K0) + kc * 4) * HD + nc * 4; \
    R[0] = *(const f32x4*)pd_;            R[1] = *(const f32x4*)(pd_ + HD); \
    R[2] = *(const f32x4*)(pd_ + 2*HD);   R[3] = *(const f32x4*)(pd_ + 3*HD); \
  } while (0)

#define STAGE_A4(KT, BUF) do { \
    const int k0s_ = (KT) * 64; \
    _Pragma("unroll") \
    for (int i_ = 0; i_ < 4; ++i_) \
      load_lds16(asrc[i_] + k0s_, &A[(BUF) * 8192 + (wid * 4 + i_) * 512]); \
  } while (0)

#define CVT_D(R) do { \
    __bf16* bd_ = (__bf16*)Bd; \
    const int xm_ = (nc & 7) << 3; \
    _Pragma("unroll") \
    for (int j_ = 0; j_ < 4; ++j_) { \
      int so_ = (nc * 4 + j_) * 72 + ((kc * 4) ^ xm_); \
      *(bf16x4*)&bd_[so_] = (bf16x4){(__bf16)R[0][j_], (__bf16)R[1][j_], (__bf16)R[2][j_], (__bf16)R[3][j_]}; \
    } \
  } while (0)

#define COMPUTE_D(CUR) do { \
    const char* Ab_ = (const char*)&A[(CUR) * 8192]; \
    const __bf16* Bd_ = (const __bf16*)Bd; \
    _Pragma("unroll") \
    for (int ks = 0; ks < 2; ++ks) { \
      bf16x8 af[4]; \
      _Pragma("unroll") \
      for (int mf = 0; mf < 4; ++mf) { \
        int row = wr * 64 + mf * 16 + (lane & 15); \
        int byte = row * 128 + (lane >> 4) * 16 + ks * 64; \
        byte ^= (row & 7) << 4; \
        af[mf] = *(const bf16x8*)(Ab_ + byte); \
      } \
      _Pragma("unroll") \
      for (int nf = 0; nf < 2; ++nf) { \
        int n = wc * 32 + nf * 16 + (lane & 15); \
        int so = n * 72 + ((((lane >> 4) * 8) + ks * 32) ^ (((n >> 2) & 7) << 3)); \
        bf16x8 bdf = *(const bf16x8*)&Bd_[so]; \
        _Pragma("unroll") \
        for (int mf = 0; mf < 4; ++mf) \
          dacc[mf][nf] = __builtin_amdgcn_mfma_f32_16x16x32_bf16(af[mf], bdf, dacc[mf][nf], 0, 0, 0); \
      } \
    } \
  } while (0)

  // prologue
  LOAD_D(0, Ra);           // 4 vm
  STAGE_A4(0, 0);          // +4
  LOAD_D(64, Rb);          // +4 -> 12
  WAITCNT("s_waitcnt vmcnt(8)");             // Ra done
  CVT_D(Ra);
  WAITCNT("s_waitcnt vmcnt(4) lgkmcnt(0)");  // A(0) done; Rb flies
  BARRIER();

  // main: 5 double-steps, computes tiles 0..9
  for (int i = 0; i < 5; ++i) {
    const int kt = 2 * i;
    STAGE_A4(kt + 1, 1);
    LOAD_D((kt + 2) * 64, Ra);
    COMPUTE_D(0);
    WAITCNT("s_waitcnt lgkmcnt(0)");
    BARRIER();
    WAITCNT("s_waitcnt vmcnt(8)");             // Rb done
    CVT_D(Rb);
    WAITCNT("s_waitcnt vmcnt(4) lgkmcnt(0)");  // A(kt+1) done
    BARRIER();

    STAGE_A4(kt + 2, 0);
    LOAD_D((kt + 3) * 64, Rb);
    COMPUTE_D(1);
    WAITCNT("s_waitcnt lgkmcnt(0)");
    BARRIER();
    WAITCNT("s_waitcnt vmcnt(8)");             // Ra done
    CVT_D(Ra);
    WAITCNT("s_waitcnt vmcnt(4) lgkmcnt(0)");  // A(kt+2) done
    BARRIER();
  }
  // tail: tiles 10, 11 (Rb = tile11; outstanding vm = 4)
  STAGE_A4(11, 1);
  COMPUTE_D(0);
  WAITCNT("s_waitcnt lgkmcnt(0)");
  BARRIER();
  WAITCNT("s_waitcnt vmcnt(4)");
  CVT_D(Rb);
  WAITCNT("s_waitcnt vmcnt(0) lgkmcnt(0)");
  BARRIER();
  COMPUTE_D(1);

#undef LOAD_D
#undef STAGE_A4
#undef CVT_D
#undef COMPUTE_D

  // epilogue: weighted atomic scatter-add
  #pragma unroll
  for (int mf = 0; mf < 4; ++mf) {
    #pragma unroll
    for (int nf = 0; nf < 2; ++nf) {
      int c = nt * 64 + wc * 32 + nf * 16 + (lane & 15);
      #pragma unroll
      for (int r = 0; r < 4; ++r) {
        int row = wr * 64 + mf * 16 + (lane >> 4) * 4 + r;
        if (mt * 128 + row < ne) {
          int tok = toks[row];
          float w = wts[row];
          atomicAdd(&out[(size_t)tok * HD + c], w * dacc[mf][nf][r]);
        }
      }
    }
  }
}

extern "C" void kernel_launch(void* const* d_in, const int* in_sizes, int n_in,
                              void* d_out, int out_size, void* d_ws, size_t ws_size,
                              hipStream_t stream) {
  const float* x  = (const float*)d_in[0];
  const float* rw = (const float*)d_in[1];
  const float* wg = (const float*)d_in[2];
  const float* wu = (const float*)d_in[3];
  const float* wd = (const float*)d_in[4];
  float* out = (float*)d_out;

  char* ws = (char*)d_ws;
  unsigned short* xb   = (unsigned short*)ws;            // 8,388,608 B
  int* cnt             = (int*)(ws + 8388608);           // 256 B
  int* tok_list        = (int*)(ws + 8388864);           // 131,072 B
  float* w_list        = (float*)(ws + 8519936);         // 131,072 B
  unsigned short* hmid = (unsigned short*)(ws + 8651008);// 50,331,648 B

  hipMemsetAsync(d_out, 0, (size_t)out_size * sizeof(float), stream);
  hipMemsetAsync(cnt, 0, NEXP * sizeof(int), stream);

  router_kernel<<<T_TOK / 4, 256, 0, stream>>>(x, rw, cnt, tok_list, w_list, xb);
  gateup_kernel<<<dim3(FD / 64, CAPE / 128, NEXP), 256, 0, stream>>>(xb, wg, wu, cnt, tok_list, hmid);
  down_kernel<<<dim3(HD / 64, CAPE / 128, NEXP), 256, 0, stream>>>(hmid, wd, cnt, tok_list, w_list, out);
}

// Round 5
// 706.860 us; speedup vs baseline: 1.2641x; 1.2641x over previous
//
#include <hip/hip_runtime.h>
#include <math.h>

#define T_TOK 2048
#define HD    2048
#define NEXP  64
#define KTOP  8
#define FD    768
#define CAPE  512

typedef float  f32x4 __attribute__((ext_vector_type(4)));
typedef __bf16 bf16x8 __attribute__((ext_vector_type(8)));
typedef __bf16 bf16x4 __attribute__((ext_vector_type(4)));

__device__ __forceinline__ void load_lds16(const void* g, void* l) {
  __builtin_amdgcn_global_load_lds(
      (const __attribute__((address_space(1))) unsigned int*)g,
      (__attribute__((address_space(3))) unsigned int*)l, 16, 0, 0);
}

#define WAITCNT(S) asm volatile(S ::: "memory")
#define PIN()      asm volatile("" ::: "memory")
#define BARRIER()  __builtin_amdgcn_s_barrier()

// ---------------- Kernel 1: router (4 tokens per block) + fused f32->bf16 ----------------
__global__ __launch_bounds__(256) void router_kernel(
    const float* __restrict__ x, const float* __restrict__ rw,
    int* __restrict__ cnt, int* __restrict__ tok_list, float* __restrict__ w_list,
    unsigned short* __restrict__ xb)
{
  const int t = threadIdx.x;
  const int tb = blockIdx.x * 4;
  __shared__ float xs[4][HD];
  __shared__ float lg[4][NEXP];

  const float4* xsrc = (const float4*)(x + (size_t)tb * HD);
  float4* xdst = (float4*)&xs[0][0];
  for (int i = t; i < 4 * HD / 4; i += 256) xdst[i] = xsrc[i];
  __syncthreads();

  {
    const int e = t >> 2, q = t & 3;
    const float* wrow = rw + (size_t)e * HD;
    float a0 = 0.f, a1 = 0.f, a2 = 0.f, a3 = 0.f;
    for (int i = 0; i < HD / 16; ++i) {
      int h = (i * 4 + q) * 4;
      float4 wv = *(const float4*)(wrow + h);
      float4 x0 = *(const float4*)&xs[0][h];
      float4 x1 = *(const float4*)&xs[1][h];
      float4 x2 = *(const float4*)&xs[2][h];
      float4 x3 = *(const float4*)&xs[3][h];
      a0 += wv.x*x0.x + wv.y*x0.y + wv.z*x0.z + wv.w*x0.w;
      a1 += wv.x*x1.x + wv.y*x1.y + wv.z*x1.z + wv.w*x1.w;
      a2 += wv.x*x2.x + wv.y*x2.y + wv.z*x2.z + wv.w*x2.w;
      a3 += wv.x*x3.x + wv.y*x3.y + wv.z*x3.z + wv.w*x3.w;
    }
    a0 += __shfl_xor(a0, 1); a0 += __shfl_xor(a0, 2);
    a1 += __shfl_xor(a1, 1); a1 += __shfl_xor(a1, 2);
    a2 += __shfl_xor(a2, 1); a2 += __shfl_xor(a2, 2);
    a3 += __shfl_xor(a3, 1); a3 += __shfl_xor(a3, 2);
    if (q == 0) { lg[0][e] = a0; lg[1][e] = a1; lg[2][e] = a2; lg[3][e] = a3; }
  }

  // fused convert of this block's 4 tokens (x rows are L1/L2-hot)
  {
    const f32x4* xs4 = (const f32x4*)(x + (size_t)tb * HD);
    bf16x4* xbd = (bf16x4*)(xb + (size_t)tb * HD);
    #pragma unroll
    for (int j = 0; j < 8; ++j) {
      f32x4 v = xs4[j * 256 + t];
      xbd[j * 256 + t] = (bf16x4){(__bf16)v[0], (__bf16)v[1], (__bf16)v[2], (__bf16)v[3]};
    }
  }
  __syncthreads();

  const int wid = t >> 6, lane = t & 63;
  float v = lg[wid][lane];
  float mx = v;
  for (int o = 32; o; o >>= 1) mx = fmaxf(mx, __shfl_xor(mx, o));
  float p = expf(v - mx);
  float s = p;
  for (int o = 32; o; o >>= 1) s += __shfl_xor(s, o);
  float prob = p / s;

  float r = prob;
  float wk[KTOP]; int ik[KTOP]; float wsum = 0.f;
  #pragma unroll
  for (int k = 0; k < KTOP; ++k) {
    float bv = r; int bl = lane;
    for (int o = 32; o; o >>= 1) {
      float ov = __shfl_xor(bv, o); int ol = __shfl_xor(bl, o);
      if (ov > bv || (ov == bv && ol < bl)) { bv = ov; bl = ol; }
    }
    wk[k] = bv; ik[k] = bl; wsum += bv;
    if (lane == bl) r = -1.f;
  }
  if (lane == 0) {
    float inv = 1.f / (wsum + 1e-20f);
    int token = tb + wid;
    #pragma unroll
    for (int k = 0; k < KTOP; ++k) {
      int ex = ik[k];
      int pos = atomicAdd(&cnt[ex], 1);
      if (pos < CAPE) {
        tok_list[ex * CAPE + pos] = token;
        w_list[ex * CAPE + pos] = wk[k] * inv;
      }
    }
  }
}

// ============ GEMM blocks: 512 threads, 8 waves (4M x 2N), wave-tile 32x32 ============
// A LDS: [m][k] dbuf, gload_lds linear granules, src pre-swizzled, read XOR ((row&7)<<4).
// B LDS: [n][k] single-buffered, stride 72 shorts, XOR ((n>>2)&7)<<3 (short units).
// Schedule: counted vmcnt (waits 6/4), 2 barriers per K-step, 2-deep B reg prefetch.

// ---------------- Kernel 3: gate/up GEMM + SiLU -> hmid (bf16) ----------------
__global__ __launch_bounds__(512, 4) void gateup_kernel(
    const unsigned short* __restrict__ xb,
    const float* __restrict__ wg, const float* __restrict__ wu,
    const int* __restrict__ cnt, const int* __restrict__ tok_list,
    unsigned short* __restrict__ hmid)
{
  const int nt = blockIdx.x, mt = blockIdx.y, e = blockIdx.z;
  int ne = cnt[e]; ne = ne < CAPE ? ne : CAPE;
  if (mt * 128 >= ne) return;
  const int t = threadIdx.x, lane = t & 63, wid = t >> 6;
  const int wr = wid >> 1, wc = wid & 1;

  __shared__ __align__(16) unsigned short A[2 * 128 * 64];   // 32 KB dbuf
  __shared__ __align__(16) unsigned short Bg[64 * 72];       // 9 KB single
  __shared__ __align__(16) unsigned short Bu[64 * 72];
  __shared__ int toks[128];

  if (t < 128) {
    int r = mt * 128 + t;
    toks[t] = tok_list[e * CAPE + (r < ne ? r : 0)];
  }
  __syncthreads();

  // A source bases: 16 granule-insts, 2 per wave
  const unsigned short* asrc[2];
  #pragma unroll
  for (int i = 0; i < 2; ++i) {
    const int inst = wid * 2 + i;
    const int G = inst * 64 + lane;
    const int m = G >> 3, gg = G & 7;
    asrc[i] = xb + (size_t)toks[m] * HD + 8 * (gg ^ (m & 7));
  }

  f32x4 z4 = {0.f, 0.f, 0.f, 0.f};
  f32x4 gacc[2][2], uacc[2][2];
  #pragma unroll
  for (int i = 0; i < 2; ++i)
    #pragma unroll
    for (int j = 0; j < 2; ++j) { gacc[i][j] = z4; uacc[i][j] = z4; }

  // B staging: waves 0-3 handle gate, waves 4-7 handle up (same 256-thread mapping)
  const int bq = t & 255, nc = bq & 15, kc = bq >> 4;
  const float* wsel = (wid < 4) ? wg : wu;
  __bf16* bsel = (wid < 4) ? (__bf16*)Bg : (__bf16*)Bu;
  const size_t wbase = (size_t)e * HD * FD + (size_t)nt * 64;
  f32x4 Ra[4], Rb[4];

#define LOAD_GU(K0, R) do { \
    const float* p_ = wsel + wbase + (size_t)((K0) + kc * 4) * FD + nc * 4; \
    R[0] = *(const f32x4*)p_;            R[1] = *(const f32x4*)(p_ + FD); \
    R[2] = *(const f32x4*)(p_ + 2*FD);   R[3] = *(const f32x4*)(p_ + 3*FD); \
  } while (0)

#define STAGE_A2(KT, BUF) do { \
    const int k0s_ = (KT) * 64; \
    load_lds16(asrc[0] + k0s_, &A[(BUF) * 8192 + (wid * 2 + 0) * 512]); \
    load_lds16(asrc[1] + k0s_, &A[(BUF) * 8192 + (wid * 2 + 1) * 512]); \
  } while (0)

#define CVT_GU(R) do { \
    const int xm_ = (nc & 7) << 3; \
    _Pragma("unroll") \
    for (int j_ = 0; j_ < 4; ++j_) { \
      int so_ = (nc * 4 + j_) * 72 + ((kc * 4) ^ xm_); \
      *(bf16x4*)&bsel[so_] = (bf16x4){(__bf16)R[0][j_], (__bf16)R[1][j_], (__bf16)R[2][j_], (__bf16)R[3][j_]}; \
    } \
  } while (0)

#define COMPUTE_GU(CUR) do { \
    const char* Ab_ = (const char*)&A[(CUR) * 8192]; \
    const __bf16* Bg_ = (const __bf16*)Bg; \
    const __bf16* Bu_ = (const __bf16*)Bu; \
    _Pragma("unroll") \
    for (int ks = 0; ks < 2; ++ks) { \
      bf16x8 af[2]; \
      _Pragma("unroll") \
      for (int mf = 0; mf < 2; ++mf) { \
        int row = wr * 32 + mf * 16 + (lane & 15); \
        int byte = row * 128 + (lane >> 4) * 16 + ks * 64; \
        byte ^= (row & 7) << 4; \
        af[mf] = *(const bf16x8*)(Ab_ + byte); \
      } \
      _Pragma("unroll") \
      for (int nf = 0; nf < 2; ++nf) { \
        int n = wc * 32 + nf * 16 + (lane & 15); \
        int so = n * 72 + ((((lane >> 4) * 8) + ks * 32) ^ (((n >> 2) & 7) << 3)); \
        bf16x8 bgf = *(const bf16x8*)&Bg_[so]; \
        bf16x8 bum = *(const bf16x8*)&Bu_[so]; \
        _Pragma("unroll") \
        for (int mf = 0; mf < 2; ++mf) { \
          gacc[mf][nf] = __builtin_amdgcn_mfma_f32_16x16x32_bf16(af[mf], bgf, gacc[mf][nf], 0, 0, 0); \
          uacc[mf][nf] = __builtin_amdgcn_mfma_f32_16x16x32_bf16(af[mf], bum, uacc[mf][nf], 0, 0, 0); \
        } \
      } \
    } \
  } while (0)

  // prologue: queue order [Ra(0):4 | A(0):2 | Rb(1):4]
  LOAD_GU(0, Ra);
  PIN();
  STAGE_A2(0, 0);
  PIN();
  LOAD_GU(64, Rb);
  WAITCNT("s_waitcnt vmcnt(6)");             // Ra done
  CVT_GU(Ra);
  WAITCNT("s_waitcnt vmcnt(4) lgkmcnt(0)");  // A(0) done; Rb flies
  BARRIER();

  // main: 15 double-steps, computes tiles 0..29
  for (int i = 0; i < 15; ++i) {
    const int kt = 2 * i;
    // half A: compute kt, CVT tile kt+1 (Rb), stage A(kt+1), load Ra(kt+2)
    STAGE_A2(kt + 1, 1);
    PIN();
    LOAD_GU((kt + 2) * 64, Ra);
    COMPUTE_GU(0);
    WAITCNT("s_waitcnt lgkmcnt(0)");
    BARRIER();                                 // all waves done reading B(kt)
    WAITCNT("s_waitcnt vmcnt(6)");             // Rb (tile kt+1) done
    CVT_GU(Rb);
    WAITCNT("s_waitcnt vmcnt(4) lgkmcnt(0)");  // A(kt+1) done; Ra flies
    BARRIER();
    // half B: compute kt+1, CVT tile kt+2 (Ra), stage A(kt+2), load Rb(kt+3)
    STAGE_A2(kt + 2, 0);
    PIN();
    LOAD_GU((kt + 3) * 64, Rb);
    COMPUTE_GU(1);
    WAITCNT("s_waitcnt lgkmcnt(0)");
    BARRIER();
    WAITCNT("s_waitcnt vmcnt(6)");             // Ra (tile kt+2) done
    CVT_GU(Ra);
    WAITCNT("s_waitcnt vmcnt(4) lgkmcnt(0)");  // A(kt+2) done; Rb flies
    BARRIER();
  }
  // tail: tiles 30, 31 (Rb = tile 31 in flight: 4 outstanding)
  STAGE_A2(31, 1);                             // +2 -> 6
  COMPUTE_GU(0);                               // tile 30 (buf 0)
  WAITCNT("s_waitcnt lgkmcnt(0)");
  BARRIER();
  WAITCNT("s_waitcnt vmcnt(2)");               // Rb done (A(31): 2 remain)
  CVT_GU(Rb);
  WAITCNT("s_waitcnt vmcnt(0) lgkmcnt(0)");
  BARRIER();
  COMPUTE_GU(1);                               // tile 31

#undef LOAD_GU
#undef STAGE_A2
#undef CVT_GU
#undef COMPUTE_GU

  // epilogue: hmid = silu(g)*u   (D layout: col=lane&15, row=4*(lane>>4)+reg)
  const size_t hbase = (size_t)e * CAPE + (size_t)mt * 128;
  __bf16* hm = (__bf16*)hmid;
  #pragma unroll
  for (int mf = 0; mf < 2; ++mf) {
    #pragma unroll
    for (int nf = 0; nf < 2; ++nf) {
      #pragma unroll
      for (int r = 0; r < 4; ++r) {
        int row = wr * 32 + mf * 16 + (lane >> 4) * 4 + r;
        int c = nt * 64 + wc * 32 + nf * 16 + (lane & 15);
        float gv = gacc[mf][nf][r], uv = uacc[mf][nf][r];
        float hv = gv / (1.f + __expf(-gv)) * uv;
        hm[(hbase + row) * FD + c] = (__bf16)hv;
      }
    }
  }
}

// ---------------- Kernel 4: down GEMM + weighted scatter-add ----------------
__global__ __launch_bounds__(512, 4) void down_kernel(
    const unsigned short* __restrict__ hmid,
    const float* __restrict__ wd,
    const int* __restrict__ cnt, const int* __restrict__ tok_list,
    const float* __restrict__ w_list, float* __restrict__ out)
{
  const int nt = blockIdx.x, mt = blockIdx.y, e = blockIdx.z;
  int ne = cnt[e]; ne = ne < CAPE ? ne : CAPE;
  if (mt * 128 >= ne) return;
  const int t = threadIdx.x, lane = t & 63, wid = t >> 6;
  const int wr = wid >> 1, wc = wid & 1;

  __shared__ __align__(16) unsigned short A[2 * 128 * 64];   // 32 KB
  __shared__ __align__(16) unsigned short Bd[64 * 72];       // 9 KB
  __shared__ int toks[128];
  __shared__ float wts[128];

  if (t < 128) {
    int r = mt * 128 + t;
    bool vv = r < ne;
    toks[t] = vv ? tok_list[e * CAPE + r] : 0;
    wts[t]  = vv ? w_list[e * CAPE + r] : 0.f;
  }
  __syncthreads();

  const size_t arow = (size_t)e * CAPE + (size_t)mt * 128;
  const unsigned short* asrc[2];
  #pragma unroll
  for (int i = 0; i < 2; ++i) {
    const int inst = wid * 2 + i;
    const int G = inst * 64 + lane;
    const int m = G >> 3, gg = G & 7;
    asrc[i] = hmid + (arow + m) * FD + 8 * (gg ^ (m & 7));
  }

  f32x4 z4 = {0.f, 0.f, 0.f, 0.f};
  f32x4 dacc[2][2];
  #pragma unroll
  for (int i = 0; i < 2; ++i)
    #pragma unroll
    for (int j = 0; j < 2; ++j) dacc[i][j] = z4;

  // B staging: waves 0-3 only (256 threads cover the 64x64 tile)
  const int bq = t & 255, nc = bq & 15, kc = bq >> 4;
  const size_t wbase = (size_t)e * FD * HD + (size_t)nt * 64;
  f32x4 Ra[4], Rb[4];

#define LOAD_D(K0, R) do { \
    const float* p_ = wd + wbase + (size_t)((K0) + kc * 4) * HD + nc * 4; \
    R[0] = *(const f32x4*)p_;            R[1] = *(const f32x4*)(p_ + HD); \
    R[2] = *(const f32x4*)(p_ + 2*HD);   R[3] = *(const f32x4*)(p_ + 3*HD); \
  } while (0)

#define STAGE_A2(KT, BUF) do { \
    const int k0s_ = (KT) * 64; \
    load_lds16(asrc[0] + k0s_, &A[(BUF) * 8192 + (wid * 2 + 0) * 512]); \
    load_lds16(asrc[1] + k0s_, &A[(BUF) * 8192 + (wid * 2 + 1) * 512]); \
  } while (0)

#define CVT_D(R) do { \
    __bf16* bd_ = (__bf16*)Bd; \
    const int xm_ = (nc & 7) << 3; \
    _Pragma("unroll") \
    for (int j_ = 0; j_ < 4; ++j_) { \
      int so_ = (nc * 4 + j_) * 72 + ((kc * 4) ^ xm_); \
      *(bf16x4*)&bd_[so_] = (bf16x4){(__bf16)R[0][j_], (__bf16)R[1][j_], (__bf16)R[2][j_], (__bf16)R[3][j_]}; \
    } \
  } while (0)

#define COMPUTE_D(CUR) do { \
    const char* Ab_ = (const char*)&A[(CUR) * 8192]; \
    const __bf16* Bd_ = (const __bf16*)Bd; \
    _Pragma("unroll") \
    for (int ks = 0; ks < 2; ++ks) { \
      bf16x8 af[2]; \
      _Pragma("unroll") \
      for (int mf = 0; mf < 2; ++mf) { \
        int row = wr * 32 + mf * 16 + (lane & 15); \
        int byte = row * 128 + (lane >> 4) * 16 + ks * 64; \
        byte ^= (row & 7) << 4; \
        af[mf] = *(const bf16x8*)(Ab_ + byte); \
      } \
      _Pragma("unroll") \
      for (int nf = 0; nf < 2; ++nf) { \
        int n = wc * 32 + nf * 16 + (lane & 15); \
        int so = n * 72 + ((((lane >> 4) * 8) + ks * 32) ^ (((n >> 2) & 7) << 3)); \
        bf16x8 bdf = *(const bf16x8*)&Bd_[so]; \
        _Pragma("unroll") \
        for (int mf = 0; mf < 2; ++mf) \
          dacc[mf][nf] = __builtin_amdgcn_mfma_f32_16x16x32_bf16(af[mf], bdf, dacc[mf][nf], 0, 0, 0); \
      } \
    } \
  } while (0)

  // prologue: waves 0-3 queue [Ra(0):4 | A:2 | Rb(1):4]; waves 4-7 queue [A:2]
  if (wid < 4) LOAD_D(0, Ra);
  PIN();
  STAGE_A2(0, 0);
  PIN();
  if (wid < 4) {
    LOAD_D(64, Rb);
    WAITCNT("s_waitcnt vmcnt(6)");
    CVT_D(Ra);
    WAITCNT("s_waitcnt vmcnt(4) lgkmcnt(0)");
  } else {
    WAITCNT("s_waitcnt vmcnt(0) lgkmcnt(0)");
  }
  BARRIER();

  // main: 5 double-steps, computes tiles 0..9
  for (int i = 0; i < 5; ++i) {
    const int kt = 2 * i;
    STAGE_A2(kt + 1, 1);
    PIN();
    if (wid < 4) LOAD_D((kt + 2) * 64, Ra);
    COMPUTE_D(0);
    WAITCNT("s_waitcnt lgkmcnt(0)");
    BARRIER();
    if (wid < 4) {
      WAITCNT("s_waitcnt vmcnt(6)");
      CVT_D(Rb);
      WAITCNT("s_waitcnt vmcnt(4) lgkmcnt(0)");
    } else {
      WAITCNT("s_waitcnt vmcnt(0) lgkmcnt(0)");
    }
    BARRIER();

    STAGE_A2(kt + 2, 0);
    PIN();
    if (wid < 4) LOAD_D((kt + 3) * 64, Rb);
    COMPUTE_D(1);
    WAITCNT("s_waitcnt lgkmcnt(0)");
    BARRIER();
    if (wid < 4) {
      WAITCNT("s_waitcnt vmcnt(6)");
      CVT_D(Ra);
      WAITCNT("s_waitcnt vmcnt(4) lgkmcnt(0)");
    } else {
      WAITCNT("s_waitcnt vmcnt(0) lgkmcnt(0)");
    }
    BARRIER();
  }
  // tail: tiles 10, 11 (Rb = tile 11 in flight for waves 0-3)
  STAGE_A2(11, 1);
  COMPUTE_D(0);
  WAITCNT("s_waitcnt lgkmcnt(0)");
  BARRIER();
  if (wid < 4) {
    WAITCNT("s_waitcnt vmcnt(2)");
    CVT_D(Rb);
    WAITCNT("s_waitcnt vmcnt(0) lgkmcnt(0)");
  } else {
    WAITCNT("s_waitcnt vmcnt(0) lgkmcnt(0)");
  }
  BARRIER();
  COMPUTE_D(1);

#undef LOAD_D
#undef STAGE_A2
#undef CVT_D
#undef COMPUTE_D

  // epilogue: weighted atomic scatter-add
  #pragma unroll
  for (int mf = 0; mf < 2; ++mf) {
    #pragma unroll
    for (int nf = 0; nf < 2; ++nf) {
      int c = nt * 64 + wc * 32 + nf * 16 + (lane & 15);
      #pragma unroll
      for (int r = 0; r < 4; ++r) {
        int row = wr * 32 + mf * 16 + (lane >> 4) * 4 + r;
        if (mt * 128 + row < ne) {
          int tok = toks[row];
          float w = wts[row];
          atomicAdd(&out[(size_t)tok * HD + c], w * dacc[mf][nf][r]);
        }
      }
    }
  }
}

extern "C" void kernel_launch(void* const* d_in, const int* in_sizes, int n_in,
                              void* d_out, int out_size, void* d_ws, size_t ws_size,
                              hipStream_t stream) {
  const float* x  = (const float*)d_in[0];
  const float* rw = (const float*)d_in[1];
  const float* wg = (const float*)d_in[2];
  const float* wu = (const float*)d_in[3];
  const float* wd = (const float*)d_in[4];
  float* out = (float*)d_out;

  char* ws = (char*)d_ws;
  unsigned short* xb   = (unsigned short*)ws;            // 8,388,608 B
  int* cnt             = (int*)(ws + 8388608);           // 256 B
  int* tok_list        = (int*)(ws + 8388864);           // 131,072 B
  float* w_list        = (float*)(ws + 8519936);         // 131,072 B
  unsigned short* hmid = (unsigned short*)(ws + 8651008);// 50,331,648 B

  hipMemsetAsync(d_out, 0, (size_t)out_size * sizeof(float), stream);
  hipMemsetAsync(cnt, 0, NEXP * sizeof(int), stream);

  router_kernel<<<T_TOK / 4, 256, 0, stream>>>(x, rw, cnt, tok_list, w_list, xb);
  gateup_kernel<<<dim3(FD / 64, CAPE / 128, NEXP), 512, 0, stream>>>(xb, wg, wu, cnt, tok_list, hmid);
  down_kernel<<<dim3(HD / 64, CAPE / 128, NEXP), 512, 0, stream>>>(hmid, wd, cnt, tok_list, w_list, out);
}